// Round 9
// baseline (229.348 us; speedup 1.0000x reference)
//
#include <hip/hip_runtime.h>
#include <hip/hip_bf16.h>
#include <math.h>

// Problem constants (fixed by the reference)
constexpr int Bn = 32768;   // batch
constexpr int Dn = 256;     // embedding dim
constexpr int Cn = 2048;    // classes
constexpr int NSPLIT = 4;                // class splits in k_main
constexpr int CLS_PER_BLK = Cn / NSPLIT; // 512
constexpr int NSUP = CLS_PER_BLK / 32;   // 16 supertiles (32 classes) per unit
constexpr int PAD = 64;                  // order_pad slots per class
#define EPSF 1e-12f
#define INFF __builtin_inff()

typedef __bf16 bf16x8 __attribute__((ext_vector_type(8)));
typedef __bf16 bf16x4 __attribute__((ext_vector_type(4)));
typedef float  f32x4  __attribute__((ext_vector_type(4)));

__device__ inline void async_copy16(const void* g, void* l) {
    __builtin_amdgcn_global_load_lds(
        (const __attribute__((address_space(1))) void*)g,
        (__attribute__((address_space(3))) void*)l, 16, 0, 0);
}

// ---------------- K1: normalize(-2x, bf16) + padded counting scatter ------
// 2048 blocks x 4 waves x 4 samples. fneg[i] = -2 * f_i (bf16).
// Scatter needs no scan: rank r = atomicAdd(cnt[l]) indexes a padded
// per-class slot array directly (overflow list for n > PAD, ~never taken).
__global__ __launch_bounds__(256) void k_prep(const float* __restrict__ feat,
                                              const int* __restrict__ labels,
                                              __bf16* __restrict__ fneg,
                                              int* __restrict__ cnt,
                                              int* __restrict__ order_pad,
                                              int* __restrict__ ovf_cnt,
                                              int* __restrict__ ovf_cls,
                                              int* __restrict__ ovf_idx) {
    const int tid = threadIdx.x;
    const int wave = tid >> 6, lane = tid & 63;
    const int base = blockIdx.x * 16 + wave * 4;
    #pragma unroll
    for (int j = 0; j < 4; ++j) {
        const int s = base + j;
        const float4 v = ((const float4*)(feat + (size_t)s * Dn))[lane];
        float ss = v.x * v.x + v.y * v.y + v.z * v.z + v.w * v.w;
        #pragma unroll
        for (int off = 1; off < 64; off <<= 1) ss += __shfl_xor(ss, off, 64);
        const float inv = -2.0f / fmaxf(sqrtf(ss), EPSF);
        bf16x4 bf;
        bf[0] = (__bf16)(v.x * inv); bf[1] = (__bf16)(v.y * inv);
        bf[2] = (__bf16)(v.z * inv); bf[3] = (__bf16)(v.w * inv);
        *(bf16x4*)(fneg + (size_t)s * Dn + lane * 4) = bf;
        if (lane == 0) {
            const int l = labels[s];
            const int r = atomicAdd(&cnt[l], 1);
            if (r < PAD) order_pad[l * PAD + r] = s;
            else {
                const int o = atomicAdd(ovf_cnt, 1);
                ovf_cls[o] = l; ovf_idx[o] = s;
            }
        }
    }
}

// ---------------- K2: per-class sums -> centK (K-major bf16) + cn2 --------
// wave per class; lane covers 4 dims. fneg holds -2f; scale by -0.5.
__global__ __launch_bounds__(256) void k_centseg(const __bf16* __restrict__ fneg,
                                                 const int* __restrict__ cnt,
                                                 const int* __restrict__ order_pad,
                                                 const int* __restrict__ ovf_cnt,
                                                 const int* __restrict__ ovf_cls,
                                                 const int* __restrict__ ovf_idx,
                                                 __bf16* __restrict__ centK,
                                                 float* __restrict__ cn2x) {
    const int wave = threadIdx.x >> 6, lane = threadIdx.x & 63;
    const int c = blockIdx.x * 4 + wave;
    const int n = cnt[c];
    const int nf = (n < PAD) ? n : PAD;
    int myidx = 0;
    if (lane < nf) myidx = order_pad[c * PAD + lane];
    float sx = 0.f, sy = 0.f, sz = 0.f, sw = 0.f;
    for (int j = 0; j < nf; ++j) {
        const int idx = __shfl(myidx, j, 64);
        const bf16x4 v = *(const bf16x4*)(fneg + (size_t)idx * Dn + lane * 4);
        sx += -0.5f * (float)v[0]; sy += -0.5f * (float)v[1];
        sz += -0.5f * (float)v[2]; sw += -0.5f * (float)v[3];
    }
    if (n > PAD) {                       // overflow fallback (~never)
        const int novf = *ovf_cnt;
        for (int j = 0; j < novf; ++j) {
            if (ovf_cls[j] == c) {
                const int idx = ovf_idx[j];
                const bf16x4 v = *(const bf16x4*)(fneg + (size_t)idx * Dn + lane * 4);
                sx += -0.5f * (float)v[0]; sy += -0.5f * (float)v[1];
                sz += -0.5f * (float)v[2]; sw += -0.5f * (float)v[3];
            }
        }
    }
    const float invn = 1.0f / fmaxf((float)n, 1.0f);
    const float cx = sx * invn, cy = sy * invn, cz = sz * invn, cw = sw * invn;
    // centK chunk (kc, c): dims [8kc,8kc+8); lane covers kc=lane>>1, half lane&1
    bf16x4 cb; cb[0] = (__bf16)cx; cb[1] = (__bf16)cy;
    cb[2] = (__bf16)cz; cb[3] = (__bf16)cw;
    *(bf16x4*)(centK + ((size_t)(lane >> 1) * Cn + c) * 8 + (lane & 1) * 4) = cb;
    float ss = cx * cx + cy * cy + cz * cz + cw * cw;
    #pragma unroll
    for (int off = 1; off < 64; off <<= 1) ss += __shfl_xor(ss, off, 64);
    if (lane == 0) cn2x[c] = (n > 0) ? ss : INFF;
}

// ---------------- K3: MFMA dot + masked min; last split does loss tail ----
// grid (Bn/256, NSPLIT); block 256 = 4 waves; wave owns 64 samples (4 tiles).
// Epilogue thinned: acc initialized to cn2 (free), own-class masked via
// cmp+cndmask, min — 3 VALU/elem. Own-class dot recomputed in the tail.
// Cross-block data (minval, tickets, accum) is atomic-only; __syncthreads'
// vmcnt(0) drain orders atomics before tickets (no fences — round-6 lesson).
__global__ __launch_bounds__(256, 2) void k_main(const __bf16* __restrict__ fneg,
                                                 const int* __restrict__ labels,
                                                 const __bf16* __restrict__ centK,
                                                 const float* __restrict__ cn2x,
                                                 const int* __restrict__ cnt,
                                                 const int* __restrict__ epoch,
                                                 float* __restrict__ minval,
                                                 float* __restrict__ accum,
                                                 int* __restrict__ ticket_bx,
                                                 int* __restrict__ ticket_fin,
                                                 float* __restrict__ out) {
    __shared__ __align__(16) __bf16 sB[3][32 * Dn];   // 3 x 16KB supertiles
    __shared__ float s_cn2[CLS_PER_BLK];               // 2KB
    const int tid = threadIdx.x;
    const int lane = tid & 63, wave = tid >> 6;
    const int m16 = lane & 15, quad = lane >> 4;
    const int sbase = blockIdx.x * 256 + wave * 64;
    const int c_begin = blockIdx.y * CLS_PER_BLK;

    // A fragments: a[p][t] = fneg[sbase+16p+m16][32t+8*quad .. +7]
    bf16x8 a[4][8];
    #pragma unroll
    for (int p = 0; p < 4; ++p) {
        const __bf16* fr = fneg + (size_t)(sbase + p * 16 + m16) * Dn + quad * 8;
        #pragma unroll
        for (int t = 0; t < 8; ++t) a[p][t] = *(const bf16x8*)(fr + t * 32);
    }
    int lab[4][4];
    #pragma unroll
    for (int p = 0; p < 4; ++p)
        #pragma unroll
        for (int r = 0; r < 4; ++r)
            lab[p][r] = labels[sbase + p * 16 + quad * 4 + r];

    float rm[4][4];
    #pragma unroll
    for (int p = 0; p < 4; ++p)
        #pragma unroll
        for (int r = 0; r < 4; ++r) rm[p][r] = INFF;

    // stage supertile s (32 classes = 1024 x 16B chunks) into sB[buf]
    auto stage = [&](int buf, int s) {
        const int c0 = c_begin + s * 32;
        #pragma unroll
        for (int j = 0; j < 4; ++j) {
            const int L = wave * 256 + j * 64 + lane;          // 0..1023
            const int st = L >> 9, kc = (L >> 4) & 31, n = L & 15;
            const __bf16* g = centK + ((size_t)kc * Cn + (c0 + st * 16 + n)) * 8;
            __bf16* l = &sB[buf][(size_t)(wave * 256 + j * 64) * 8]; // wave-uniform
            async_copy16(g, l);
        }
    };

    stage(0, 0);
    stage(1, 1);
    for (int c = tid; c < CLS_PER_BLK; c += 256) s_cn2[c] = cn2x[c_begin + c];
    for (int s = 0; s < NSUP; ++s) {
        __syncthreads();
        if (s + 2 < NSUP) stage((s + 2) % 3, s + 2);
        const __bf16* lsb = &sB[s % 3][0];
        #pragma unroll
        for (int st = 0; st < 2; ++st) {
            const float cn2v = s_cn2[s * 32 + st * 16 + m16];
            const __bf16* ls = lsb + st * 4096;
            f32x4 acc[4];
            #pragma unroll
            for (int p = 0; p < 4; ++p)
                acc[p] = f32x4{cn2v, cn2v, cn2v, cn2v};   // free cn2 add
            #pragma unroll
            for (int t = 0; t < 8; ++t) {
                const bf16x8 b = *(const bf16x8*)(ls + t * 512 + lane * 8);
                #pragma unroll
                for (int p = 0; p < 4; ++p)
                    acc[p] = __builtin_amdgcn_mfma_f32_16x16x32_bf16(a[p][t], b, acc[p], 0, 0, 0);
            }
            const int crow = c_begin + s * 32 + st * 16 + m16;
            #pragma unroll
            for (int p = 0; p < 4; ++p)
                #pragma unroll
                for (int r = 0; r < 4; ++r)
                    rm[p][r] = fminf(rm[p][r],
                                     (crow == lab[p][r]) ? INFF : acc[p][r]);
        }
    }
    #pragma unroll
    for (int off = 1; off < 16; off <<= 1)
        #pragma unroll
        for (int p = 0; p < 4; ++p)
            #pragma unroll
            for (int r = 0; r < 4; ++r)
                rm[p][r] = fminf(rm[p][r], __shfl_xor(rm[p][r], off, 64));
    if (m16 == 0) {
        float* mv = minval + (size_t)blockIdx.y * Bn;
        #pragma unroll
        for (int p = 0; p < 4; ++p)
            #pragma unroll
            for (int r = 0; r < 4; ++r)
                atomicExch(&mv[sbase + p * 16 + quad * 4 + r], rm[p][r]);
    }

    // ---- tail: last split for this bx computes loss for its 256 samples --
    __shared__ int s_tail;
    __syncthreads();                       // drains vmcnt -> minval atomics done
    if (tid == 0)
        s_tail = (atomicAdd(&ticket_bx[blockIdx.x], 1) == NSPLIT - 1) ? 1 : 0;
    __syncthreads();
    if (!s_tail) return;

    const float temp = fminf(0.3f + 0.02f * (float)(*epoch), 1.0f);
    float ws = 0.0f, wc = 0.0f;
    const int ibase = blockIdx.x * 256 + wave * 64;
    for (int j = 0; j < 64; ++j) {
        const int i = ibase + j;
        const int l = labels[i];
        // dot = fneg[i] . cent[l] = -2 * (f . c_own)
        const bf16x4 fv = *(const bf16x4*)(fneg + (size_t)i * Dn + lane * 4);
        const bf16x4 cv = *(const bf16x4*)(centK
                              + ((size_t)(lane >> 1) * Cn + l) * 8 + (lane & 1) * 4);
        float s4 = (float)fv[0] * (float)cv[0] + (float)fv[1] * (float)cv[1]
                 + (float)fv[2] * (float)cv[2] + (float)fv[3] * (float)cv[3];
        #pragma unroll
        for (int off = 1; off < 64; off <<= 1) s4 += __shfl_xor(s4, off, 64);
        float mk = (lane < NSPLIT) ? atomicAdd(&minval[(size_t)lane * Bn + i], 0.0f)
                                   : INFF;
        mk = fminf(mk, __shfl_xor(mk, 1, 64));
        mk = fminf(mk, __shfl_xor(mk, 2, 64));
        if (lane == 0) {
            const int n = cnt[l];
            const float nf2 = (float)n;
            const float cn2 = cn2x[l];           // finite (n >= 1)
            const float fds = nf2 * (-0.5f * s4);        // f.s
            const float fm1 = fmaxf(nf2 - 1.0f, 1.0f);
            const float fdcp = (fds - 1.0f) / fm1;
            const float cp2 = (nf2 * nf2 * cn2 - 2.0f * fds + 1.0f) / (fm1 * fm1);
            const float dp2 = 1.0f - 2.0f * fdcp + cp2;
            const float d_p = sqrtf(fmaxf(dp2, 0.0f) + EPSF);
            const bool finite = (mk < 1e37f);
            const float d_n = finite ? sqrtf(fmaxf(1.0f + mk, EPSF)) : 0.0f;
            const bool valid = (n > 1) && finite;
            const float x = (d_p - d_n) / temp;
            const float sp = fmaxf(x, 0.0f) + log1pf(expf(-fabsf(x)));
            ws += valid ? sp : 0.0f;
            wc += valid ? 1.0f : 0.0f;
        }
    }
    if (lane == 0) {
        atomicAdd(&accum[0], ws);
        atomicAdd(&accum[1], wc);
    }
    // ---- very last tail block writes the output ----
    __shared__ int s_fin;
    __syncthreads();                       // drains vmcnt -> accum atomics done
    if (tid == 0)
        s_fin = (atomicAdd(ticket_fin, 1) == (Bn / 256) - 1) ? 1 : 0;
    __syncthreads();
    if (s_fin && tid == 0) {
        const float ss = atomicAdd(&accum[0], 0.0f);   // coherent read
        const float cc = atomicAdd(&accum[1], 0.0f);
        out[0] = (cc > 0.0f) ? (ss / fmaxf(cc, 1.0f)) : 0.0f;   // WEIGHT = 1.0
    }
}

// ---------------- launch ---------------------------------------------------
extern "C" void kernel_launch(void* const* d_in, const int* in_sizes, int n_in,
                              void* d_out, int out_size, void* d_ws, size_t ws_size,
                              hipStream_t stream) {
    const float* feat  = (const float*)d_in[0];
    const int* labels  = (const int*)d_in[1];
    const int* epoch   = (const int*)d_in[2];
    float* out = (float*)d_out;
    char* ws = (char*)d_ws;

    size_t off = 0;
    __bf16* fneg     = (__bf16*)(ws + off); off += (size_t)Bn * Dn * 2;    // 16 MiB
    __bf16* centK    = (__bf16*)(ws + off); off += (size_t)Cn * Dn * 2;    //  1 MiB
    float*  cn2x     = (float*)(ws + off);  off += (size_t)Cn * 4;
    int*    order_pad= (int*)(ws + off);    off += (size_t)Cn * PAD * 4;   // 512 KiB
    int*    ovf_cls  = (int*)(ws + off);    off += 256 * 4;
    int*    ovf_idx  = (int*)(ws + off);    off += 256 * 4;
    float*  minval   = (float*)(ws + off);  off += (size_t)NSPLIT * Bn * 4;// 512 KiB
    // single contiguous zeroed region: cnt | ovf_cnt | ticket_fin | accum | ticket_bx
    int*    cnt      = (int*)(ws + off);    off += (size_t)Cn * 4;
    int*    ovf_cnt  = (int*)(ws + off);    off += 4;
    int*    tick_fin = (int*)(ws + off);    off += 4;
    float*  accum    = (float*)(ws + off);  off += 2 * 4;
    int*    tick_bx  = (int*)(ws + off);    off += (Bn / 256) * 4;

    const size_t zbytes = (size_t)Cn * 4 + 4 + 4 + 8 + (Bn / 256) * 4;
    (void)hipMemsetAsync(cnt, 0, zbytes, stream);

    k_prep<<<Bn / 16, 256, 0, stream>>>(feat, labels, fneg, cnt, order_pad,
                                        ovf_cnt, ovf_cls, ovf_idx);
    k_centseg<<<Cn / 4, 256, 0, stream>>>(fneg, cnt, order_pad, ovf_cnt, ovf_cls,
                                          ovf_idx, centK, cn2x);
    dim3 g3(Bn / 256, NSPLIT);
    k_main<<<g3, 256, 0, stream>>>(fneg, labels, centK, cn2x, cnt, epoch,
                                   minval, accum, tick_bx, tick_fin, out);
}